// Round 2
// 258.253 us; speedup vs baseline: 1.0079x; 1.0079x over previous
//
#include <hip/hip_runtime.h>

// Causal bag-of-words: out[b,t,c] = mean(x[b,0..t,c]).
// Three-pass chunked scan along T. fp32 throughout.
//
// Shapes: B=8, T=8192, C=512 (row-major B,T,C). All float32.
// Pass 1: per-(b,chunk,c4) chunk sums -> ws   (float4 ws[B][NCH][C4], 4 MiB)
// Pass 2: block-parallel exclusive prefix scan of ws over the chunk axis
//         (one 256-thread block per (b,c4) column, LDS Hillis-Steele).
// Pass 3: load one exclusive-prefix float4, stream chunk of x with 8-deep
//         register batching, running sum, multiply by rcp(t+1), nontemporal
//         store (keeps x L3-resident for this second read).

constexpr int B   = 8;
constexpr int T   = 8192;
constexpr int C   = 512;
constexpr int C4  = C / 4;    // 128 float4 per (b,t) row
constexpr int L   = 32;       // chunk length along T
constexpr int NCH = T / L;    // 256 chunks

typedef float f32x4 __attribute__((ext_vector_type(4)));

__device__ __forceinline__ float4 f4add(float4 a, float4 b) {
    return make_float4(a.x + b.x, a.y + b.y, a.z + b.z, a.w + b.w);
}

__global__ __launch_bounds__(256) void cbow_chunksums(
        const float4* __restrict__ x, float4* __restrict__ ws) {
    const int tid   = blockIdx.x * blockDim.x + threadIdx.x; // [0, B*NCH*C4)
    const int c4    = tid & (C4 - 1);
    const int chunk = (tid >> 7) & (NCH - 1);
    const int b     = tid >> 15;

    const float4* p = x + ((b * T) + chunk * L) * C4 + c4;
    float4 s = make_float4(0.f, 0.f, 0.f, 0.f);
    float4 buf[8];
    for (int tt = 0; tt < L; tt += 8) {
#pragma unroll
        for (int k = 0; k < 8; ++k) buf[k] = p[(tt + k) * C4];
#pragma unroll
        for (int k = 0; k < 8; ++k) s = f4add(s, buf[k]);
    }
    ws[(b * NCH + chunk) * C4 + c4] = s;
}

// One block per (b, c4) column: exclusive scan over NCH=256 chunk sums.
__global__ __launch_bounds__(256) void cbow_wscan(float4* __restrict__ ws) {
    const int bc = blockIdx.x;        // [0, B*C4)
    const int b  = bc >> 7;
    const int c4 = bc & (C4 - 1);
    const int t  = threadIdx.x;       // chunk index, == NCH

    __shared__ float4 sm[NCH];

    float4 v = ws[(b * NCH + t) * C4 + c4];
    sm[t] = v;
    __syncthreads();

#pragma unroll
    for (int off = 1; off < NCH; off <<= 1) {
        float4 tmp = (t >= off) ? sm[t - off]
                                : make_float4(0.f, 0.f, 0.f, 0.f);
        __syncthreads();
        v = f4add(v, tmp);
        sm[t] = v;
        __syncthreads();
    }

    const float4 excl = (t > 0) ? sm[t - 1] : make_float4(0.f, 0.f, 0.f, 0.f);
    ws[(b * NCH + t) * C4 + c4] = excl;
}

__global__ __launch_bounds__(256) void cbow_scan(
        const float4* __restrict__ x, const float4* __restrict__ ws,
        float4* __restrict__ out) {
    const int tid   = blockIdx.x * blockDim.x + threadIdx.x;
    const int c4    = tid & (C4 - 1);
    const int chunk = (tid >> 7) & (NCH - 1);
    const int b     = tid >> 15;

    // Exclusive prefix of all preceding chunks: a single L2-resident load.
    float4 run = ws[(b * NCH + chunk) * C4 + c4];

    const int     base = ((b * T) + chunk * L) * C4 + c4;
    const float4* p    = x + base;
    float4*       o    = out + base;
    const int     t0   = chunk * L;

    float4 buf[8];
    for (int tt = 0; tt < L; tt += 8) {
#pragma unroll
        for (int k = 0; k < 8; ++k) buf[k] = p[(tt + k) * C4];
#pragma unroll
        for (int k = 0; k < 8; ++k) {
            run = f4add(run, buf[k]);
            const float inv = __builtin_amdgcn_rcpf((float)(t0 + tt + k + 1));
            f32x4 val = {run.x * inv, run.y * inv, run.z * inv, run.w * inv};
            __builtin_nontemporal_store(val, (f32x4*)(o + (tt + k) * C4));
        }
    }
}

extern "C" void kernel_launch(void* const* d_in, const int* in_sizes, int n_in,
                              void* d_out, int out_size, void* d_ws, size_t ws_size,
                              hipStream_t stream) {
    const float4* x   = (const float4*)d_in[0];
    float4*       out = (float4*)d_out;
    float4*       ws  = (float4*)d_ws;   // needs B*NCH*C4*16 = 4 MiB

    const int n_threads = B * NCH * C4;  // 262144
    const int block = 256;
    const int grid  = n_threads / block; // 1024

    cbow_chunksums<<<grid, block, 0, stream>>>(x, ws);
    cbow_wscan<<<B * C4, block, 0, stream>>>(ws);
    cbow_scan<<<grid, block, 0, stream>>>(x, ws, out);
}